// Round 4
// baseline (55.651 us; speedup 1.0000x reference)
//
#include <hip/hip_runtime.h>

// Problem constants from reference: B=16, S=4096, F=1024, units fp32, mask int32.
#define B_ 16
#define S_ 4096
#define F_ 1024
#define F4_ (F_ / 4)   // float4 per output row = 256
#define ROWS_ 8        // output token rows per scatter block

// One block per batch row. 1024 threads; each thread scans 4 mask elems (int4).
// Produces src[b*S_ + p] = s for the p-th masked subtoken of row b, and lens[b].
__global__ __launch_bounds__(1024) void pos_kernel(const int* __restrict__ mask,
                                                   int* __restrict__ src,
                                                   int* __restrict__ lens) {
    const int b   = blockIdx.x;
    const int tid = threadIdx.x;

    const int4 m = ((const int4*)(mask + b * S_))[tid];
    const int local = m.x + m.y + m.z + m.w;

    const int lane = tid & 63;
    const int wid  = tid >> 6;

    // wave-inclusive scan of per-thread sums
    int incl = local;
#pragma unroll
    for (int d = 1; d < 64; d <<= 1) {
        int n = __shfl_up(incl, d, 64);
        if (lane >= d) incl += n;
    }

    __shared__ int wsum[16];
    __shared__ int woff[16];
    if (lane == 63) wsum[wid] = incl;
    __syncthreads();
    // wave 0, lanes 0..15: shuffle-scan the 16 wave sums (exclusive)
    if (wid == 0) {
        int v = (lane < 16) ? wsum[lane] : 0;
        int iscan = v;
#pragma unroll
        for (int d = 1; d < 16; d <<= 1) {
            int n = __shfl_up(iscan, d, 64);
            if (lane >= d) iscan += n;
        }
        if (lane < 16) woff[lane] = iscan - v;   // exclusive
        if (lane == 15) lens[b] = iscan;         // total
    }
    __syncthreads();

    int p = woff[wid] + (incl - local);   // exclusive prefix for this thread
    const int s0 = tid * 4;
    int* srow = src + b * S_;
    if (m.x) srow[p++] = s0;
    if (m.y) srow[p++] = s0 + 1;
    if (m.z) srow[p++] = s0 + 2;
    if (m.w) srow[p]   = s0 + 3;
}

// ROWS_ output token rows per block (grid: ceil(T/ROWS_) x B). 256 threads.
// Each thread: ROWS_ independent 16B gather loads, then ROWS_ contiguous 16B stores.
__global__ __launch_bounds__(F4_) void scatter_kernel(const float4* __restrict__ units,
                                                      const int* __restrict__ src,
                                                      const int* __restrict__ lens,
                                                      float4* __restrict__ out, int T) {
    const int b  = blockIdx.y;
    const int t0 = blockIdx.x * ROWS_;
    const int len = lens[b];                 // block-uniform
    const int* srow = src + b * S_;

    float4 v[ROWS_];
    const float4 zero = make_float4(0.f, 0.f, 0.f, 0.f);
#pragma unroll
    for (int i = 0; i < ROWS_; ++i) {
        const int t = t0 + i;
        if (t < len) {
            const int s = srow[t];           // block-uniform
            v[i] = units[((size_t)(b * S_ + s)) * F4_ + threadIdx.x];
        } else {
            v[i] = zero;
        }
    }

    const size_t obase = ((size_t)b * (size_t)T + t0) * F4_ + threadIdx.x;
#pragma unroll
    for (int i = 0; i < ROWS_; ++i) {
        if (t0 + i < T) out[obase + (size_t)i * F4_] = v[i];
    }
}

extern "C" void kernel_launch(void* const* d_in, const int* in_sizes, int n_in,
                              void* d_out, int out_size, void* d_ws, size_t ws_size,
                              hipStream_t stream) {
    const float* units = (const float*)d_in[0];
    const int*   mask  = (const int*)d_in[1];
    float*       out   = (float*)d_out;

    const int T = out_size / (B_ * F_);   // harness sized d_out as B*T*F

    int* src  = (int*)d_ws;               // B_*S_ ints
    int* lens = src + B_ * S_;            // B_ ints

    pos_kernel<<<B_, 1024, 0, stream>>>(mask, src, lens);

    dim3 grid((unsigned)((T + ROWS_ - 1) / ROWS_), B_);
    scatter_kernel<<<grid, F4_, 0, stream>>>((const float4*)units, src, lens,
                                             (float4*)out, T);
}

// Round 5
// 53.703 us; speedup vs baseline: 1.0363x; 1.0363x over previous
//
#include <hip/hip_runtime.h>

// Problem constants from reference: B=16, S=4096, F=1024, units fp32, mask int32.
#define B_ 16
#define S_ 4096
#define F_ 1024
#define F4_ (F_ / 4)    // float4 per output row = 256
#define ROWS_ 8         // output token rows per block
#define NT_ 256         // threads per block
#define EPT_ (S_ / NT_) // mask elements per thread = 16

// Fused kernel: grid (ceil(T/ROWS_), B). Each block:
//  1) scans the whole mask row (redundantly, L2-hot) -> len + this block's
//     ROWS_ source indices (ranks t0..t0+ROWS_-1) into LDS,
//  2) gathers those unit rows and writes them (or zeros) to out.
__global__ __launch_bounds__(NT_) void fused_kernel(const float4* __restrict__ units,
                                                    const int* __restrict__ mask,
                                                    float4* __restrict__ out, int T) {
    const int b   = blockIdx.y;
    const int t0  = blockIdx.x * ROWS_;
    const int tid = threadIdx.x;
    const int lane = tid & 63;
    const int wid  = tid >> 6;           // 4 waves

    // ---- 1) block scan of mask row ----
    const int4* mrow = (const int4*)(mask + b * S_);
    int4 m[EPT_ / 4];
#pragma unroll
    for (int k = 0; k < EPT_ / 4; ++k) m[k] = mrow[tid * (EPT_ / 4) + k];

    int local = 0;
#pragma unroll
    for (int k = 0; k < EPT_ / 4; ++k) local += m[k].x + m[k].y + m[k].z + m[k].w;

    // wave-inclusive scan of per-thread sums
    int incl = local;
#pragma unroll
    for (int d = 1; d < 64; d <<= 1) {
        int n = __shfl_up(incl, d, 64);
        if (lane >= d) incl += n;
    }

    __shared__ int wsum[4];
    __shared__ int woff[4];
    __shared__ int slen;
    __shared__ int ssrc[ROWS_];
    if (lane == 63) wsum[wid] = incl;
    __syncthreads();
    if (tid == 0) {
        int acc = 0;
#pragma unroll
        for (int w = 0; w < 4; ++w) { woff[w] = acc; acc += wsum[w]; }
        slen = acc;
    }
    __syncthreads();

    // thread-exclusive rank of first set bit owned by this thread
    int r = woff[wid] + (incl - local);
    const int s0 = tid * EPT_;
    // deposit source indices for ranks within [t0, t0+ROWS_)
#pragma unroll
    for (int k = 0; k < EPT_ / 4; ++k) {
        const int mv[4] = {m[k].x, m[k].y, m[k].z, m[k].w};
#pragma unroll
        for (int j = 0; j < 4; ++j) {
            if (mv[j]) {
                const unsigned rel = (unsigned)(r - t0);
                if (rel < (unsigned)ROWS_) ssrc[rel] = s0 + k * 4 + j;
                ++r;
            }
        }
    }
    __syncthreads();

    const int len = slen;

    // ---- 2) gather + store ROWS_ output rows ----
    float4 v[ROWS_];
    const float4 zero = make_float4(0.f, 0.f, 0.f, 0.f);
#pragma unroll
    for (int i = 0; i < ROWS_; ++i) {
        const int t = t0 + i;
        if (t < len) {
            const int s = ssrc[i];
            v[i] = units[((size_t)(b * S_ + s)) * F4_ + tid];
        } else {
            v[i] = zero;
        }
    }

    const size_t obase = ((size_t)b * (size_t)T + t0) * F4_ + tid;
#pragma unroll
    for (int i = 0; i < ROWS_; ++i) {
        if (t0 + i < T) out[obase + (size_t)i * F4_] = v[i];
    }
}

extern "C" void kernel_launch(void* const* d_in, const int* in_sizes, int n_in,
                              void* d_out, int out_size, void* d_ws, size_t ws_size,
                              hipStream_t stream) {
    const float* units = (const float*)d_in[0];
    const int*   mask  = (const int*)d_in[1];
    float*       out   = (float*)d_out;

    const int T = out_size / (B_ * F_);   // harness sized d_out as B*T*F

    dim3 grid((unsigned)((T + ROWS_ - 1) / ROWS_), B_);
    fused_kernel<<<grid, NT_, 0, stream>>>((const float4*)units, mask,
                                           (float4*)out, T);
}